// Round 1
// baseline (1234.045 us; speedup 1.0000x reference)
//
#include <hip/hip_runtime.h>
#include <hip/hip_bf16.h>
#include <math.h>

// N=100000, D=128, H=8, HID=256, QK=64, V=64, PSI_HID=256, OUT=128
#define NPTS 100000
#define NPAD 100032
#define NTILES 1563

typedef __bf16 bf16x8 __attribute__((ext_vector_type(8)));
typedef float f32x4 __attribute__((ext_vector_type(4)));

#define MFMA16(a, b, c) __builtin_amdgcn_mfma_f32_16x16x32_bf16((a), (b), (c), 0, 0, 0)

// Generic cast+transpose: src (B,R,C) f32 -> dst (B,C,R) bf16
__global__ void k_cast_transpose(const float* __restrict__ src, __bf16* __restrict__ dst,
                                 int B, int R, int C) {
  int total = B * R * C;
  for (int idx = blockIdx.x * 256 + threadIdx.x; idx < total; idx += gridDim.x * 256) {
    int b = idx / (R * C);
    int rem = idx - b * R * C;
    int r = rem / C;
    int c = rem - r * C;
    dst[((size_t)b * C + c) * R + r] = (__bf16)src[idx];
  }
}

// Phase A: per (head, 64-row tile): q/k/v 2-layer MLPs (bf16 MFMA, fp32 accum),
// store phi(q) to scratch; kv += kk^T @ v and sumk += colsum(kk) via atomics.
__global__ __launch_bounds__(256) void k_phaseA(
    const float* __restrict__ coords, const float* __restrict__ mask,
    const __bf16* __restrict__ W0t,   // [3][8][256][128]  (m-major, k=d contiguous)
    const __bf16* __restrict__ W1t,   // [3][8][64][256]   (o-major, k=m contiguous)
    const float* __restrict__ bq0, const float* __restrict__ bq1,
    const float* __restrict__ bk0, const float* __restrict__ bk1,
    const float* __restrict__ bv0, const float* __restrict__ bv1,
    __bf16* __restrict__ qk_ws,       // [8][NPAD][64]
    float* __restrict__ kv,           // [8][64][64]
    float* __restrict__ sumk)         // [8][64]
{
  const int h = blockIdx.x;
  const int tile = blockIdx.y;
  const int tid = threadIdx.x;
  const int lane = tid & 63;
  const int w = tid >> 6;          // wave 0..3
  const int l15 = lane & 15;
  const int lg = lane >> 4;        // 0..3

  __shared__ __bf16 sX[64 * 128];  // 16KB, swizzled
  __shared__ __bf16 sW0[64 * 128]; // 16KB, B chunk layer1 (col-major rows)
  __shared__ __bf16 sW1[64 * 64];  // 8KB,  B chunk layer2
  __shared__ __bf16 sHc[64 * 64];  // 8KB,  hidden chunk
  __shared__ __bf16 sKK[64 * 64];  // 8KB
  __shared__ __bf16 sV[64 * 64];   // 8KB   -> total 64KB, 2 blocks/CU

  // stage X tile, f32 -> bf16, zero-pad rows >= NPTS
  #pragma unroll
  for (int i = 0; i < 4; ++i) {
    int c = tid + i * 256;          // 0..1023 chunks of 8 elems
    int row = c >> 4;
    int e8 = (c & 15) << 3;
    int grow = tile * 64 + row;
    bf16x8 vv = {};
    if (grow < NPTS) {
      const float4* p = (const float4*)(coords + (size_t)grow * 128 + e8);
      float4 f0 = p[0], f1 = p[1];
      vv[0] = (__bf16)f0.x; vv[1] = (__bf16)f0.y; vv[2] = (__bf16)f0.z; vv[3] = (__bf16)f0.w;
      vv[4] = (__bf16)f1.x; vv[5] = (__bf16)f1.y; vv[6] = (__bf16)f1.z; vv[7] = (__bf16)f1.w;
    }
    *(bf16x8*)&sX[((row << 7) + e8) ^ ((row & 7) << 3)] = vv;
  }

  for (int m = 0; m < 3; ++m) {     // 0=q, 1=k, 2=v
    const __bf16* w0 = W0t + (size_t)(m * 8 + h) * 32768;
    const __bf16* w1 = W1t + (size_t)(m * 8 + h) * 16384;
    const float* b0 = (m == 0) ? bq0 : (m == 1) ? bk0 : bv0;
    const float* b1 = (m == 0) ? bq1 : (m == 1) ? bk1 : bv1;

    f32x4 acc2[4] = {};

    for (int c = 0; c < 4; ++c) {   // hidden chunks of 64
      __syncthreads();              // protect sW0/sW1/sHc (and sX on first pass)
      // stage W0 chunk: cols c*64..c*64+63 x k 0..127
      #pragma unroll
      for (int i = 0; i < 4; ++i) {
        int cc = tid + i * 256;
        int bc = cc >> 4;
        int e8 = (cc & 15) << 3;
        bf16x8 vv = *(const bf16x8*)(w0 + (size_t)(c * 64 + bc) * 128 + e8);
        *(bf16x8*)&sW0[((bc << 7) + e8) ^ ((bc & 7) << 3)] = vv;
      }
      // stage W1 chunk: out-cols 0..63 x k c*64..c*64+63
      #pragma unroll
      for (int i = 0; i < 2; ++i) {
        int cc = tid + i * 256;
        int oc = cc >> 3;
        int e8 = (cc & 7) << 3;
        bf16x8 vv = *(const bf16x8*)(w1 + (size_t)oc * 256 + c * 64 + e8);
        *(bf16x8*)&sW1[((oc << 6) + e8) ^ ((oc & 7) << 3)] = vv;
      }
      __syncthreads();

      // layer1: Hc = relu(X @ W0c + b0c)
      f32x4 acc1[4] = {};
      #pragma unroll
      for (int kk = 0; kk < 4; ++kk) {
        int arow = (w << 4) + l15;
        int ak = (kk << 5) + (lg << 3);
        bf16x8 av = *(const bf16x8*)&sX[((arow << 7) + ak) ^ ((arow & 7) << 3)];
        #pragma unroll
        for (int f = 0; f < 4; ++f) {
          int bc = (f << 4) + l15;
          bf16x8 bv = *(const bf16x8*)&sW0[((bc << 7) + ak) ^ ((bc & 7) << 3)];
          acc1[f] = MFMA16(av, bv, acc1[f]);
        }
      }
      #pragma unroll
      for (int f = 0; f < 4; ++f) {
        int colc = (f << 4) + l15;
        float bias = b0[(h << 8) + (c << 6) + colc];
        #pragma unroll
        for (int r = 0; r < 4; ++r) {
          int row = (w << 4) + (lg << 2) + r;
          float val = acc1[f][r] + bias;
          val = val > 0.f ? val : 0.f;
          sHc[((row << 6) + colc) ^ ((row & 7) << 3)] = (__bf16)val;
        }
      }
      __syncthreads();
      // layer2 partial: acc2 += Hc @ W1c
      #pragma unroll
      for (int ks = 0; ks < 2; ++ks) {
        int arow = (w << 4) + l15;
        int ak = (ks << 5) + (lg << 3);
        bf16x8 av = *(const bf16x8*)&sHc[((arow << 6) + ak) ^ ((arow & 7) << 3)];
        #pragma unroll
        for (int f = 0; f < 4; ++f) {
          int bc = (f << 4) + l15;
          bf16x8 bv = *(const bf16x8*)&sW1[((bc << 6) + ak) ^ ((bc & 7) << 3)];
          acc2[f] = MFMA16(av, bv, acc2[f]);
        }
      }
    }

    // epilogue for this mat
    #pragma unroll
    for (int f = 0; f < 4; ++f) {
      int col = (f << 4) + l15;
      float b1v = b1[(h << 6) + col];
      #pragma unroll
      for (int r = 0; r < 4; ++r) {
        int row = (w << 4) + (lg << 2) + r;
        int grow = tile * 64 + row;
        float mval = (grow < NPTS) ? mask[grow] : 0.f;
        float val = (acc2[f][r] + b1v) * mval;
        if (m == 0) {
          float pq = val > 0.f ? val + 1.f : expf(val);  // elu(x)+1
          qk_ws[((size_t)h * NPAD + grow) * 64 + col] = (__bf16)pq;
        } else if (m == 1) {
          // pad rows must contribute 0 (phi(0)=1 would pollute kv/sumk)
          float pk = (grow < NPTS) ? (val > 0.f ? val + 1.f : expf(val)) : 0.f;
          sKK[(row << 6) + col] = (__bf16)pk;
        } else {
          sV[(row << 6) + col] = (__bf16)val;
        }
      }
    }
  }

  __syncthreads();
  // kv[kq][j] += sum_n kk[n][kq] * v[n][j]  (MFMA, transposed A reads from LDS)
  f32x4 akv[4] = {};
  #pragma unroll
  for (int ks = 0; ks < 2; ++ks) {
    int kq = (w << 4) + l15;
    int nb = (ks << 5) + (lg << 3);
    bf16x8 av;
    #pragma unroll
    for (int e = 0; e < 8; ++e) av[e] = sKK[((nb + e) << 6) + kq];
    #pragma unroll
    for (int f = 0; f < 4; ++f) {
      int j = (f << 4) + l15;
      bf16x8 bv;
      #pragma unroll
      for (int e = 0; e < 8; ++e) bv[e] = sV[((nb + e) << 6) + j];
      akv[f] = MFMA16(av, bv, akv[f]);
    }
  }
  #pragma unroll
  for (int f = 0; f < 4; ++f) {
    #pragma unroll
    for (int r = 0; r < 4; ++r) {
      int kq = (w << 4) + (lg << 2) + r;
      int j = (f << 4) + l15;
      atomicAdd(&kv[(size_t)((h << 6) + kq) * 64 + j], akv[f][r]);
    }
  }
  if (tid < 64) {
    float s = 0.f;
    for (int n = 0; n < 64; ++n) s += (float)sKK[(n << 6) + tid];
    atomicAdd(&sumk[(h << 6) + tid], s);
  }
}

// kv (f32, [8][k][j]) -> kvT (bf16, [8][j][k]) for K-contiguous B-fragments
__global__ void k_kvt(const float* __restrict__ kv, __bf16* __restrict__ kvT) {
  int idx = blockIdx.x * 256 + threadIdx.x;
  if (idx < 8 * 64 * 64) {
    int hh = idx >> 12;
    int rem = idx & 4095;
    int k = rem >> 6;
    int j = rem & 63;
    kvT[(size_t)((hh << 6) + j) * 64 + k] = (__bf16)kv[idx];
  }
}

// Phase C+D: per 64-row tile: for each head: den, num = qk@kv, cat chunk in LDS,
// incrementally accumulate psi layer1; then relu -> LDS -> layer2 -> out.
__global__ __launch_bounds__(256) void k_cd(
    const float* __restrict__ mask, const __bf16* __restrict__ qk_ws,
    const __bf16* __restrict__ kvT, const float* __restrict__ sumk,
    const __bf16* __restrict__ Wp0t,  // [256][512]
    const __bf16* __restrict__ Wp1t,  // [128][256]
    const float* __restrict__ bp0, const float* __restrict__ bp1,
    float* __restrict__ out)
{
  const int tile = blockIdx.x;
  const int tid = threadIdx.x;
  const int lane = tid & 63;
  const int w = tid >> 6;
  const int l15 = lane & 15;
  const int lg = lane >> 4;

  __shared__ __bf16 sCat[64 * 64];   // 8KB per-head cat chunk, swizzled
  __shared__ __bf16 sH2[64 * 256];   // 32KB psi hidden, swizzled
  __shared__ float sSumk[512];
  __shared__ float sDen[64];

  sSumk[tid] = sumk[tid];
  sSumk[tid + 256] = sumk[tid + 256];
  __syncthreads();

  f32x4 acc1[16] = {};   // psi layer1 accumulator: 16 rows x 256 cols per wave

  for (int h = 0; h < 8; ++h) {
    // num = qk @ kv   (A-fragments straight from global qk scratch)
    f32x4 accn[4] = {};
    #pragma unroll
    for (int ks = 0; ks < 2; ++ks) {
      int arow = tile * 64 + (w << 4) + l15;
      int ak = (ks << 5) + (lg << 3);
      bf16x8 av = *(const bf16x8*)&qk_ws[((size_t)h * NPAD + arow) * 64 + ak];
      #pragma unroll
      for (int f = 0; f < 4; ++f) {
        int j = (f << 4) + l15;
        bf16x8 bv = *(const bf16x8*)&kvT[(size_t)((h << 6) + j) * 64 + ak];
        accn[f] = MFMA16(av, bv, accn[f]);
      }
    }
    // den by wave 0
    if (tid < 64) {
      int grow = tile * 64 + tid;
      const __bf16* qrow = qk_ws + ((size_t)h * NPAD + grow) * 64;
      float s = 0.f;
      #pragma unroll
      for (int jj = 0; jj < 8; ++jj) {
        bf16x8 qv = *(const bf16x8*)(qrow + (jj << 3));
        #pragma unroll
        for (int e = 0; e < 8; ++e) s += (float)qv[e] * sSumk[(h << 6) + (jj << 3) + e];
      }
      sDen[tid] = (s == 0.f) ? 1e-6f : s;
    }
    __syncthreads();
    // cat chunk = num / den
    #pragma unroll
    for (int f = 0; f < 4; ++f) {
      #pragma unroll
      for (int r = 0; r < 4; ++r) {
        int row = (w << 4) + (lg << 2) + r;
        int col = (f << 4) + l15;
        float cv = accn[f][r] / sDen[row];
        sCat[((row << 6) + col) ^ ((row & 7) << 3)] = (__bf16)cv;
      }
    }
    __syncthreads();
    // psi layer1 partial: acc1 += cat_h @ Wp0[h*64 .. h*64+64, :]
    #pragma unroll
    for (int ks = 0; ks < 2; ++ks) {
      int arow = (w << 4) + l15;
      int akl = (ks << 5) + (lg << 3);
      bf16x8 av = *(const bf16x8*)&sCat[((arow << 6) + akl) ^ ((arow & 7) << 3)];
      int kg = (h << 6) + akl;
      #pragma unroll
      for (int f = 0; f < 16; ++f) {
        int col = (f << 4) + l15;
        bf16x8 bv = *(const bf16x8*)&Wp0t[(size_t)col * 512 + kg];
        acc1[f] = MFMA16(av, bv, acc1[f]);
      }
    }
    __syncthreads();  // before next head rewrites sCat/sDen
  }

  // H2 = relu(acc1 + bp0)
  #pragma unroll
  for (int f = 0; f < 16; ++f) {
    int col = (f << 4) + l15;
    float bias = bp0[col];
    #pragma unroll
    for (int r = 0; r < 4; ++r) {
      int row = (w << 4) + (lg << 2) + r;
      float val = acc1[f][r] + bias;
      val = val > 0.f ? val : 0.f;
      sH2[((row << 8) + col) ^ ((row & 7) << 3)] = (__bf16)val;
    }
  }
  __syncthreads();

  // out = (H2 @ Wp1 + bp1) * mask
  f32x4 acc2[8] = {};
  #pragma unroll
  for (int kk = 0; kk < 8; ++kk) {
    int arow = (w << 4) + l15;
    int ak = (kk << 5) + (lg << 3);
    bf16x8 av = *(const bf16x8*)&sH2[((arow << 8) + ak) ^ ((arow & 7) << 3)];
    #pragma unroll
    for (int f = 0; f < 8; ++f) {
      int col = (f << 4) + l15;
      bf16x8 bv = *(const bf16x8*)&Wp1t[(size_t)col * 256 + ak];
      acc2[f] = MFMA16(av, bv, acc2[f]);
    }
  }
  #pragma unroll
  for (int f = 0; f < 8; ++f) {
    int col = (f << 4) + l15;
    float bias = bp1[col];
    #pragma unroll
    for (int r = 0; r < 4; ++r) {
      int row = (w << 4) + (lg << 2) + r;
      int grow = tile * 64 + row;
      if (grow < NPTS) {
        float val = (acc2[f][r] + bias) * mask[grow];
        out[(size_t)grow * 128 + col] = val;
      }
    }
  }
}

extern "C" void kernel_launch(void* const* d_in, const int* in_sizes, int n_in,
                              void* d_out, int out_size, void* d_ws, size_t ws_size,
                              hipStream_t stream) {
  const float* coords = (const float*)d_in[0];
  const float* mask   = (const float*)d_in[1];
  const float* Wq0 = (const float*)d_in[2];
  const float* bq0 = (const float*)d_in[3];
  const float* Wq1 = (const float*)d_in[4];
  const float* bq1 = (const float*)d_in[5];
  const float* Wk0 = (const float*)d_in[6];
  const float* bk0 = (const float*)d_in[7];
  const float* Wk1 = (const float*)d_in[8];
  const float* bk1 = (const float*)d_in[9];
  const float* Wv0 = (const float*)d_in[10];
  const float* bv0 = (const float*)d_in[11];
  const float* Wv1 = (const float*)d_in[12];
  const float* bv1 = (const float*)d_in[13];
  const float* Wp0 = (const float*)d_in[14];
  const float* bp0 = (const float*)d_in[15];
  const float* Wp1 = (const float*)d_in[16];
  const float* bp1 = (const float*)d_in[17];
  float* out = (float*)d_out;

  // workspace carve-up (all 16B-aligned; total ~100.4 MB)
  char* p = (char*)d_ws;
  __bf16* qk_ws = (__bf16*)p; p += (size_t)8 * NPAD * 64 * 2;       // 102,432,768
  __bf16* W0t   = (__bf16*)p; p += (size_t)3 * 8 * 256 * 128 * 2;   //   1,572,864
  __bf16* W1t   = (__bf16*)p; p += (size_t)3 * 8 * 64 * 256 * 2;    //     786,432
  __bf16* Wp0t  = (__bf16*)p; p += (size_t)256 * 512 * 2;           //     262,144
  __bf16* Wp1t  = (__bf16*)p; p += (size_t)128 * 256 * 2;           //      65,536
  float*  kv    = (float*)p;  p += (size_t)8 * 64 * 64 * 4;         //     131,072
  float*  sumk  = (float*)p;  p += (size_t)8 * 64 * 4;              //       2,048
  __bf16* kvT   = (__bf16*)p; p += (size_t)8 * 64 * 64 * 2;         //      65,536

  // zero the atomic accumulators (kv + sumk are contiguous) every call
  hipMemsetAsync(kv, 0, (8 * 64 * 64 + 8 * 64) * sizeof(float), stream);

  // weight prep: cast to bf16 with K-contiguous (transposed) layouts
  k_cast_transpose<<<256, 256, 0, stream>>>(Wq0, W0t,          8, 128, 256);
  k_cast_transpose<<<256, 256, 0, stream>>>(Wk0, W0t + 262144, 8, 128, 256);
  k_cast_transpose<<<256, 256, 0, stream>>>(Wv0, W0t + 524288, 8, 128, 256);
  k_cast_transpose<<<256, 256, 0, stream>>>(Wq1, W1t,          8, 256, 64);
  k_cast_transpose<<<256, 256, 0, stream>>>(Wk1, W1t + 131072, 8, 256, 64);
  k_cast_transpose<<<256, 256, 0, stream>>>(Wv1, W1t + 262144, 8, 256, 64);
  k_cast_transpose<<<128, 256, 0, stream>>>(Wp0, Wp0t,         1, 512, 256);
  k_cast_transpose<<<64,  256, 0, stream>>>(Wp1, Wp1t,         1, 256, 128);

  dim3 gA(8, NTILES);
  k_phaseA<<<gA, 256, 0, stream>>>(coords, mask, W0t, W1t, bq0, bq1, bk0, bk1,
                                   bv0, bv1, qk_ws, kv, sumk);
  k_kvt<<<128, 256, 0, stream>>>(kv, kvT);
  k_cd<<<NTILES, 256, 0, stream>>>(mask, qk_ws, kvT, sumk, Wp0t, Wp1t, bp0, bp1, out);
}